// Round 17
// baseline (128.839 us; speedup 1.0000x reference)
//
#include <hip/hip_runtime.h>
#include <hip/hip_bf16.h>

typedef __attribute__((ext_vector_type(8))) short bf16x8;
typedef __attribute__((ext_vector_type(4))) float f32x4;

#define D128 128
#define IMG_SHORTS 16384          // one W frag-image: 32 frags x 64 lanes x 8 bf16 = 32 KB
#define XB_OFF 65536              // xb at 128 KiB into d_ws (in shorts)
#define NBLK 256
#define WSH (3 * IMG_SHORTS)      // 96 KB of W images (shorts)
#define RBS 4096                  // per-wave: src rows [0,2048), dst rows [2048,4096) shorts

__device__ __forceinline__ short f2bf(float f) {
    union { float f; unsigned u; } v; v.f = f;
    unsigned r = (v.u + 0x7FFFu + ((v.u >> 16) & 1u)) >> 16;  // RNE
    return (short)r;
}

__device__ __forceinline__ short f2bf_h(float f) {
    __hip_bfloat16 h = __float2bfloat16(f);
    short s;
    __builtin_memcpy(&s, &h, sizeof(short));
    return s;
}

__device__ __forceinline__ bf16x8 pack8(f32x4 a, f32x4 b) {
    bf16x8 r;
    r[0] = f2bf_h(a[0]); r[1] = f2bf_h(a[1]); r[2] = f2bf_h(a[2]); r[3] = f2bf_h(a[3]);
    r[4] = f2bf_h(b[0]); r[5] = f2bf_h(b[1]); r[6] = f2bf_h(b[2]); r[7] = f2bf_h(b[3]);
    return r;
}

__device__ __forceinline__ void gload_lds16(const short* g, short* l) {
    __builtin_amdgcn_global_load_lds(
        (const __attribute__((address_space(1))) unsigned int*)(const void*)g,
        (__attribute__((address_space(3))) unsigned int*)(void*)l, 16, 0, 0);
}

// W (3*128 x 128 fp32 row-major) -> 3 A-operand fragment images (src,dst,e):
// img[c][frag=mt*4+ks][lane][j] = W[c*128 + ks*32 + (lane>>4)*8 + j][mt*16 + (lane&15)]
__global__ __launch_bounds__(256) void wt_kernel(const float* __restrict__ W,
                                                 short* __restrict__ Wimg) {
    const int c    = blockIdx.x >> 3;
    const int frag = (blockIdx.x & 7) * 4 + (threadIdx.x >> 6);
    const int lane = threadIdx.x & 63;
    const int mt = frag >> 2, ks = frag & 3;
    const int m  = mt * 16 + (lane & 15);
    const int k0 = ks * 32 + (lane >> 4) * 8;
    bf16x8 v;
#pragma unroll
    for (int j = 0; j < 8; ++j)
        v[j] = f2bf(W[(size_t)(c * 128 + k0 + j) * D128 + m]);
    *reinterpret_cast<bf16x8*>(
        &Wimg[((size_t)c * 32 + frag) * 64 * 8 + (size_t)lane * 8]) = v;
}

// x (fp32) -> xb (bf16), 8 elems/thread.
__global__ __launch_bounds__(256) void xb_kernel(const float* __restrict__ x,
                                                 short* __restrict__ xb) {
    const size_t i = ((size_t)blockIdx.x * 256 + threadIdx.x) * 8;
    f32x4 v0 = reinterpret_cast<const f32x4*>(x + i)[0];
    f32x4 v1 = reinterpret_cast<const f32x4*>(x + i)[1];
    *reinterpret_cast<bf16x8*>(xb + i) = pack8(v0, v1);
}

// Fused kernel = R13 structure (silicon-proven vmcnt ledger, 8 waves, 160KB
// LDS, quad-coalesced gather DMA) with two LDS-issue reductions that leave
// the VM-op sequence and all waits byte-identical:
//  1. e-loads and out-stores are direct fragment-shaped (R11-proven) — the
//     LDS bounce rounds are removed (-32 LDS ops/iter, timing-neutral VM-wise)
//  2. 24 of 32 e-chunk W fragments hoisted to registers before the loop
//     (loop-invariant; -24 ds_read_b128 per iteration)
__global__ __launch_bounds__(512, 2) void fused_kernel(
        const short* __restrict__ xb,
        const float* __restrict__ e,
        const short* __restrict__ Wimg,
        const int*  __restrict__ src_idx,
        const int*  __restrict__ dst_idx,
        float* __restrict__ out,
        int E, int ntiles)
{
    __shared__ short lds[WSH + 8 * RBS];   // 160 KB exact

    const int tid  = threadIdx.x;
    const int lane = tid & 63;
    const int w    = tid >> 6;            // 0..7
    const int r    = lane >> 2;           // row this lane's gather DMA serves
    const int q    = lane & 3;            // 16B quarter of the 64B span
    const int sx   = (r >> 1) & 3;        // XOR twist
    const int fr   = lane & 15;           // frag row this lane computes
    const int lhi  = lane >> 4;           // frag k-quarter
    const int rb_off = (fr * 4 + (lhi ^ ((fr >> 1) & 3))) * 8;   // readback slot

    short* RB = &lds[WSH + w * RBS];      // src rows, 4 KB
    short* BB = RB + 2048;                // dst rows, 4 KB

    // contiguous tile range for this block
    const int per = ntiles >> 8;
    const int rem = ntiles & 255;
    const int b   = blockIdx.x;
    const int t0  = b * per + (b < rem ? b : rem);
    const int t1  = t0 + per + (b < rem ? 1 : 0);

    // ---- prologue: stage W images (12 DMA/thread, linear both sides) ----
#pragma unroll
    for (int jj = 0; jj < 12; ++jj) {
        int unit = jj * 512 + tid;
        gload_lds16(Wimg + (size_t)unit * 8, &lds[unit * 8]);
    }
    int rp = t0 * 128 + w * 16 + r;
    int si = src_idx[rp];
    int di = dst_idx[rp];
    asm volatile("" ::: "memory");
    asm volatile("s_waitcnt vmcnt(0)" ::: "memory");
    __builtin_amdgcn_s_barrier();          // the only barrier

    // ---- hoist 24 e-chunk W fragments to registers (loop-invariant) ----
    bf16x8 wa_e[24];
#pragma unroll
    for (int mt = 0; mt < 6; ++mt)
#pragma unroll
        for (int ks = 0; ks < 4; ++ks)
            wa_e[mt * 4 + ks] = *reinterpret_cast<const bf16x8*>(
                &lds[((2 * 32 + mt * 4 + ks) * 64 + lane) * 8]);

    // ---- DMA src[t0]: quad-coalesced source, linear LDS dest ----
#pragma unroll
    for (int ks = 0; ks < 4; ++ks)
        gload_lds16(xb + (size_t)si * D128 + ks * 32 + (q ^ sx) * 8, &RB[ks * 512]);
    asm volatile("" ::: "memory");

    for (int t = t0; t < t1; ++t) {
        const int rn = t * 128 + w * 16 + fr;    // compute/e/store row (frag-shaped)

        // ---- issue DMA dst[t] (4, quad-coalesced) into BB ----
#pragma unroll
        for (int ks = 0; ks < 4; ++ks)
            gload_lds16(xb + (size_t)di * D128 + ks * 32 + (q ^ sx) * 8,
                        &BB[ks * 512]);
        asm volatile("" ::: "memory");

        // ---- issue e loads (8, fragment-shaped; R11-proven) ----
        const float* pe = e + (size_t)rn * D128;
        f32x4 ev[8];
#pragma unroll
        for (int ks = 0; ks < 4; ++ks) {
            ev[2 * ks]     = reinterpret_cast<const f32x4*>(pe + ks * 32 + lhi * 8)[0];
            ev[2 * ks + 1] = reinterpret_cast<const f32x4*>(pe + ks * 32 + lhi * 8)[1];
        }
        asm volatile("" ::: "memory");

        // ---- issue idx[t+1] (2) ----
        int rpn = (t + 1) * 128 + w * 16 + r;
        if (rpn >= E) rpn = E - 1;
        const int sin_ = src_idx[rpn];
        const int din_ = dst_idx[rpn];
        asm volatile("" ::: "memory");

        // src[t] ready (retires backedge src'4+stores8+idx; dst4+e8+idx2 fly)
        asm volatile("s_waitcnt vmcnt(14)" ::: "memory");
        __builtin_amdgcn_sched_barrier(0);

        f32x4 acc[8];
#pragma unroll
        for (int mt = 0; mt < 8; ++mt) acc[mt] = (f32x4){0.f, 0.f, 0.f, 0.f};

        // ---- chunk 0: src rows from RB, twisted slot readback ----
#pragma unroll
        for (int ks = 0; ks < 4; ++ks) {
            bf16x8 bfr = *reinterpret_cast<const bf16x8*>(&RB[ks * 512 + rb_off]);
#pragma unroll
            for (int mt = 0; mt < 8; ++mt) {
                bf16x8 a = *reinterpret_cast<const bf16x8*>(
                    &lds[((0 * 32 + mt * 4 + ks) * 64 + lane) * 8]);
                acc[mt] = __builtin_amdgcn_mfma_f32_16x16x32_bf16(a, bfr, acc[mt], 0, 0, 0);
            }
        }

        // dst[t] ready (e8+idx2 fly)
        asm volatile("s_waitcnt vmcnt(10)" ::: "memory");
        __builtin_amdgcn_sched_barrier(0);

        // ---- chunk 1: dst rows from BB ----
#pragma unroll
        for (int ks = 0; ks < 4; ++ks) {
            bf16x8 bfr = *reinterpret_cast<const bf16x8*>(&BB[ks * 512 + rb_off]);
#pragma unroll
            for (int mt = 0; mt < 8; ++mt) {
                bf16x8 a = *reinterpret_cast<const bf16x8*>(
                    &lds[((1 * 32 + mt * 4 + ks) * 64 + lane) * 8]);
                acc[mt] = __builtin_amdgcn_mfma_f32_16x16x32_bf16(a, bfr, acc[mt], 0, 0, 0);
            }
        }
        asm volatile("" ::: "memory");

        // ---- issue DMA src[t+1] (4) into RB (chunk-0 reads retired) ----
#pragma unroll
        for (int ks = 0; ks < 4; ++ks)
            gload_lds16(xb + (size_t)sin_ * D128 + ks * 32 + (q ^ sx) * 8, &RB[ks * 512]);
        asm volatile("" ::: "memory");
        si = sin_; di = din_;

        // e ready (idx2 + src'4 fly)
        asm volatile("s_waitcnt vmcnt(6)" ::: "memory");
        __builtin_amdgcn_sched_barrier(0);

        // ---- chunk 2: e — pack, MFMA with hoisted W frags (mt<6) ----
#pragma unroll
        for (int ks = 0; ks < 4; ++ks) {
            bf16x8 be = pack8(ev[2 * ks], ev[2 * ks + 1]);
#pragma unroll
            for (int mt = 0; mt < 6; ++mt)
                acc[mt] = __builtin_amdgcn_mfma_f32_16x16x32_bf16(
                    wa_e[mt * 4 + ks], be, acc[mt], 0, 0, 0);
#pragma unroll
            for (int mt = 6; mt < 8; ++mt) {
                bf16x8 a = *reinterpret_cast<const bf16x8*>(
                    &lds[((2 * 32 + mt * 4 + ks) * 64 + lane) * 8]);
                acc[mt] = __builtin_amdgcn_mfma_f32_16x16x32_bf16(a, be, acc[mt], 0, 0, 0);
            }
        }

        // ---- epilogue: lane owns out[rn][mt*16 + lhi*4 .. +3] (R11-proven) ----
        float* po = out + (size_t)rn * D128 + lhi * 4;
#pragma unroll
        for (int mt = 0; mt < 8; ++mt)
            *reinterpret_cast<f32x4*>(po + mt * 16) = acc[mt];
        asm volatile("" ::: "memory");   // stores precede next iter's issues
    }
}

extern "C" void kernel_launch(void* const* d_in, const int* in_sizes, int n_in,
                              void* d_out, int out_size, void* d_ws, size_t ws_size,
                              hipStream_t stream) {
    const float* x = (const float*)d_in[0];
    const float* e = (const float*)d_in[1];
    const float* W = (const float*)d_in[2];
    const int* src = (const int*)d_in[3];
    const int* dst = (const int*)d_in[4];
    float* out = (float*)d_out;

    short* Wimg = (short*)d_ws;                 // 3 x 32 KB frag images
    short* xb   = (short*)d_ws + XB_OFF;        // 100000*128 bf16 = 25.6 MB

    const int N = in_sizes[0] / D128;           // 100000
    const int E = in_sizes[3];                  // 400000
    const int ntiles = E / 128;                 // 3125 (exact)

    wt_kernel<<<24, 256, 0, stream>>>(W, Wimg);
    xb_kernel<<<(N * D128) / (256 * 8), 256, 0, stream>>>(x, xb);
    fused_kernel<<<NBLK, 512, 0, stream>>>(xb, e, Wimg, src, dst, out, E, ntiles);
}